// Round 1
// 547.024 us; speedup vs baseline: 1.1032x; 1.1032x over previous
//
#include <hip/hip_runtime.h>
#include <hip/hip_bf16.h>

// GCN: 3x GCNConv (512->128->64->32) + global max pool + FC(32->10) + log_softmax
// N=100000 nodes, E=1600000 edges, 64 graphs.
//
// Round 7:
//  - fill_slab was latency-bound (VALUBusy 0.4%, 10.7% HBM, 122us): fused it with
//    GEMM1 in one kernel (block-interleaved), deferring layer-1 dinv scaling into
//    the gather (which now loads dinv[src] per neighbor). Latency-bound fill waves
//    hide under MFMA/BW-bound GEMM waves.
//  - fill does 4 edges/thread: 4 independent atomic chains in flight per lane.
//  - gather main loop widened to 8 neighbors/iter (mean degree 16) for MLP.

typedef __attribute__((ext_vector_type(8))) short short8;
typedef __attribute__((ext_vector_type(8))) unsigned short ushort8v;
typedef __attribute__((ext_vector_type(4))) float f32x4;

__device__ __forceinline__ unsigned short f2bf(float f) {
    __hip_bfloat16 h = __float2bfloat16(f);
    return *(unsigned short*)&h;
}
__device__ __forceinline__ float bfu2f(unsigned short u) {
    unsigned int v = ((unsigned int)u) << 16;
    return __uint_as_float(v);
}

// ---------------- init: zero slab counters + pooled ----------------
__global__ void init_kernel(int* __restrict__ cnt, float* __restrict__ pooled, int N) {
    int i = blockIdx.x * 256 + threadIdx.x;
    if (i < N) cnt[i] = 0;
    if (i < 64 * 32) pooled[i] = 0.0f;  // post-relu values >= 0
}

__global__ void dinv_kernel(const int* __restrict__ cnt, float* __restrict__ dinv, int N) {
    int i = blockIdx.x * 256 + threadIdx.x;
    if (i < N) dinv[i] = rsqrtf(1.0f + (float)cnt[i]);  // +1 self loop
}

// ---------------- W[K][N] f32 -> Wt[N][K] bf16 ----------------
__global__ void wconv(const float* __restrict__ W, unsigned short* __restrict__ Wt,
                      int K, int N) {
    int idx = blockIdx.x * 256 + threadIdx.x;
    if (idx < N * K) {
        int n = idx / K, k = idx % K;
        Wt[idx] = f2bf(W[(size_t)k * N + n]);
    }
}

// ---------------- MFMA GEMM body: C_bf16[M x NOUT] = (dinv?) .* (A[M x K] @ Wt^T) ----
template <int NOUT, bool A_BF16, bool SCALE>
__device__ __forceinline__ void gemm_body(
        int bid,
        const float* __restrict__ Af, const unsigned short* __restrict__ Ab,
        const unsigned short* __restrict__ Wt, const float* __restrict__ dinv,
        unsigned short* __restrict__ C, int M, int K) {
    constexpr int NT = NOUT / 16;            // col tiles per wave: 8/4/2
    constexpr int CH = 136;                  // shorts per chunk (16*8 + 8 pad)

    __shared__ short As[16 * CH];            // 16 chunks (4 rowgroups x 4 kquads)
    __shared__ short Bs[NT * 4 * CH];        // NT*4 chunks

    const int t = threadIdx.x;
    const int w = t >> 6;                    // wave 0..3
    const int lane = t & 63;
    const int row0 = bid * 64;

    f32x4 acc[NT];
#pragma unroll
    for (int c = 0; c < NT; ++c) acc[c] = (f32x4){0.f, 0.f, 0.f, 0.f};

    const int ar = t >> 2;                   // A row 0..63
    const int aq = t & 3;                    // A k-quad
    const int arow = row0 + ar;
    const int a_lds = ((ar >> 4) * 4 + aq) * CH + (ar & 15) * 8;

    const int bn = t >> 1;                   // Wt row (col of W)
    const int bh = t & 1;                    // k-half
    const int b_lds0 = ((bn >> 4) * 4 + 2 * bh) * CH + (bn & 15) * 8;

    for (int k0 = 0; k0 < K; k0 += 32) {
        short8 apack;
        if (A_BF16) {
            if (arow < M) apack = *(const short8*)&Ab[(size_t)arow * K + k0 + aq * 8];
            else apack = (short8){0, 0, 0, 0, 0, 0, 0, 0};
        } else {
            float4 u0 = make_float4(0.f, 0.f, 0.f, 0.f), u1 = u0;
            if (arow < M) {
                const float* ap = Af + (size_t)arow * K + k0 + aq * 8;
                u0 = *(const float4*)ap;
                u1 = *(const float4*)(ap + 4);
            }
            apack[0] = (short)f2bf(u0.x); apack[1] = (short)f2bf(u0.y);
            apack[2] = (short)f2bf(u0.z); apack[3] = (short)f2bf(u0.w);
            apack[4] = (short)f2bf(u1.x); apack[5] = (short)f2bf(u1.y);
            apack[6] = (short)f2bf(u1.z); apack[7] = (short)f2bf(u1.w);
        }
        short8 w0, w1;
        if (t < 2 * NOUT) {
            const unsigned short* wp = Wt + (size_t)bn * K + k0 + 16 * bh;
            w0 = *(const short8*)wp;
            w1 = *(const short8*)(wp + 8);
        }
        __syncthreads();
        *(short8*)&As[a_lds] = apack;
        if (t < 2 * NOUT) {
            *(short8*)&Bs[b_lds0] = w0;
            *(short8*)&Bs[b_lds0 + CH] = w1;
        }
        __syncthreads();

        short8 a = *(short8*)&As[(w * 4 + (lane >> 4)) * CH + (lane & 15) * 8];
#pragma unroll
        for (int c = 0; c < NT; ++c) {
            short8 b = *(short8*)&Bs[(c * 4 + (lane >> 4)) * CH + (lane & 15) * 8];
            acc[c] = __builtin_amdgcn_mfma_f32_16x16x32_bf16(a, b, acc[c], 0, 0, 0);
        }
    }

    const int q = lane >> 4, i = lane & 15;
#pragma unroll
    for (int reg = 0; reg < 4; ++reg) {
        int row = row0 + w * 16 + q * 4 + reg;
        if (row < M) {
            float di = SCALE ? dinv[row] : 1.0f;
#pragma unroll
            for (int c = 0; c < NT; ++c)
                C[(size_t)row * NOUT + c * 16 + i] = f2bf(di * acc[c][reg]);
        }
    }
}

template <int NOUT, bool A_BF16>
__global__ __launch_bounds__(256) void mfma_gemm(
        const float* __restrict__ Af, const unsigned short* __restrict__ Ab,
        const unsigned short* __restrict__ Wt, const float* __restrict__ dinv,
        unsigned short* __restrict__ C, int M, int K) {
    gemm_body<NOUT, A_BF16, true>(blockIdx.x, Af, Ab, Wt, dinv, C, M, K);
}

// ---------------- fused: GEMM1 (no dinv) + one-pass slab fill, block-interleaved ----
__global__ __launch_bounds__(256) void gemm1_fill(
        const float* __restrict__ x, const unsigned short* __restrict__ Wt,
        unsigned short* __restrict__ C, int M, int K,
        const int* __restrict__ src, const int* __restrict__ dst,
        int* __restrict__ cnt, int* __restrict__ slab, int E,
        int gb, int fb) {
    const int bx = blockIdx.x;
    const int m = gb < fb ? gb : fb;
    bool isg;
    int bid;
    if (bx < 2 * m) {            // interleave so both kinds are co-resident
        isg = (bx & 1) == 0;
        bid = bx >> 1;
    } else {
        bid = bx - m;
        isg = (gb > fb);
    }
    if (isg) {
        gemm_body<128, false, false>(bid, x, nullptr, Wt, nullptr, C, M, K);
    } else {
        int e0 = bid * 1024 + (int)threadIdx.x * 4;   // 4 edges/thread -> 4 chains in flight
        if (e0 + 4 <= E) {
            int d0 = dst[e0], d1 = dst[e0 + 1], d2 = dst[e0 + 2], d3 = dst[e0 + 3];
            int s0 = src[e0], s1 = src[e0 + 1], s2 = src[e0 + 2], s3 = src[e0 + 3];
            int p0 = atomicAdd(&cnt[d0], 1);
            int p1 = atomicAdd(&cnt[d1], 1);
            int p2 = atomicAdd(&cnt[d2], 1);
            int p3 = atomicAdd(&cnt[d3], 1);
            if (p0 < 64) slab[(size_t)d0 * 64 + p0] = s0;
            if (p1 < 64) slab[(size_t)d1 * 64 + p1] = s1;
            if (p2 < 64) slab[(size_t)d2 * 64 + p2] = s2;
            if (p3 < 64) slab[(size_t)d3 * 64 + p3] = s3;
        } else {
            for (int e = e0; e < E; ++e) {
                int d = dst[e];
                int p = atomicAdd(&cnt[d], 1);
                if (p < 64) slab[(size_t)d * 64 + p] = src[e];
            }
        }
    }
}

// ---------------- gather (bf16 hs, slab adjacency) ----------------
// PRESCALED: hs already carries dinv (layers 2,3): out = relu(di*(hs[i] + sum hs[s]) + b)
// !PRESCALED: hs is plain h (layer 1):            out = relu(di*(di*h[i] + sum dinv[s]*h[s]) + b)
template <int F, bool OUT_BF16, bool PRESCALED>
__global__ void gather_relu(const int* __restrict__ cnt, const int* __restrict__ slab,
                            const float* __restrict__ dinv,
                            const unsigned short* __restrict__ hs,
                            const float* __restrict__ bias, void* __restrict__ outv, int N) {
    constexpr int F8 = F / 8;          // lanes per node (16/8/4)
    constexpr int NPB = 256 / F8;
    const int node = blockIdx.x * NPB + threadIdx.x / F8;
    if (node >= N) return;
    const int lane = threadIdx.x % F8;
    const size_t fo = (size_t)lane * 8;
    const float di = dinv[node];

    float acc[8];
    {
        ushort8v s = *(const ushort8v*)&hs[(size_t)node * F + fo];
#pragma unroll
        for (int i = 0; i < 8; ++i) acc[i] = PRESCALED ? bfu2f(s[i]) : di * bfu2f(s[i]);
    }
    int deg = cnt[node];
    if (deg > 64) deg = 64;
    const int* sl = slab + (size_t)node * 64;

    int j = 0;
    for (; j + 8 <= deg; j += 8) {
        int4 a4 = *(const int4*)&sl[j];
        int4 b4 = *(const int4*)&sl[j + 4];
        ushort8v v0 = *(const ushort8v*)&hs[(size_t)a4.x * F + fo];
        ushort8v v1 = *(const ushort8v*)&hs[(size_t)a4.y * F + fo];
        ushort8v v2 = *(const ushort8v*)&hs[(size_t)a4.z * F + fo];
        ushort8v v3 = *(const ushort8v*)&hs[(size_t)a4.w * F + fo];
        ushort8v v4 = *(const ushort8v*)&hs[(size_t)b4.x * F + fo];
        ushort8v v5 = *(const ushort8v*)&hs[(size_t)b4.y * F + fo];
        ushort8v v6 = *(const ushort8v*)&hs[(size_t)b4.z * F + fo];
        ushort8v v7 = *(const ushort8v*)&hs[(size_t)b4.w * F + fo];
        if (PRESCALED) {
#pragma unroll
            for (int i = 0; i < 8; ++i)
                acc[i] += ((bfu2f(v0[i]) + bfu2f(v1[i])) + (bfu2f(v2[i]) + bfu2f(v3[i]))) +
                          ((bfu2f(v4[i]) + bfu2f(v5[i])) + (bfu2f(v6[i]) + bfu2f(v7[i])));
        } else {
            float w0 = dinv[a4.x], w1 = dinv[a4.y], w2 = dinv[a4.z], w3 = dinv[a4.w];
            float w4 = dinv[b4.x], w5 = dinv[b4.y], w6 = dinv[b4.z], w7 = dinv[b4.w];
#pragma unroll
            for (int i = 0; i < 8; ++i) {
                float s01 = fmaf(w0, bfu2f(v0[i]), w1 * bfu2f(v1[i]));
                float s23 = fmaf(w2, bfu2f(v2[i]), w3 * bfu2f(v3[i]));
                float s45 = fmaf(w4, bfu2f(v4[i]), w5 * bfu2f(v5[i]));
                float s67 = fmaf(w6, bfu2f(v6[i]), w7 * bfu2f(v7[i]));
                acc[i] += (s01 + s23) + (s45 + s67);
            }
        }
    }
    for (; j + 4 <= deg; j += 4) {
        int4 s4 = *(const int4*)&sl[j];
        ushort8v v0 = *(const ushort8v*)&hs[(size_t)s4.x * F + fo];
        ushort8v v1 = *(const ushort8v*)&hs[(size_t)s4.y * F + fo];
        ushort8v v2 = *(const ushort8v*)&hs[(size_t)s4.z * F + fo];
        ushort8v v3 = *(const ushort8v*)&hs[(size_t)s4.w * F + fo];
        if (PRESCALED) {
#pragma unroll
            for (int i = 0; i < 8; ++i)
                acc[i] += (bfu2f(v0[i]) + bfu2f(v1[i])) + (bfu2f(v2[i]) + bfu2f(v3[i]));
        } else {
            float w0 = dinv[s4.x], w1 = dinv[s4.y], w2 = dinv[s4.z], w3 = dinv[s4.w];
#pragma unroll
            for (int i = 0; i < 8; ++i) {
                float s01 = fmaf(w0, bfu2f(v0[i]), w1 * bfu2f(v1[i]));
                float s23 = fmaf(w2, bfu2f(v2[i]), w3 * bfu2f(v3[i]));
                acc[i] += s01 + s23;
            }
        }
    }
    for (; j < deg; ++j) {
        int s = sl[j];
        ushort8v v = *(const ushort8v*)&hs[(size_t)s * F + fo];
        float w = PRESCALED ? 1.0f : dinv[s];
#pragma unroll
        for (int i = 0; i < 8; ++i) acc[i] = fmaf(w, bfu2f(v[i]), acc[i]);
    }

    if (OUT_BF16) {
        ushort8v o;
#pragma unroll
        for (int i = 0; i < 8; ++i) o[i] = f2bf(fmaxf(di * acc[i] + bias[fo + i], 0.f));
        *(ushort8v*)&((unsigned short*)outv)[(size_t)node * F + fo] = o;
    } else {
        float ov[8];
#pragma unroll
        for (int i = 0; i < 8; ++i) ov[i] = fmaxf(di * acc[i] + bias[fo + i], 0.f);
        float4* op = (float4*)&((float*)outv)[(size_t)node * F + fo];
        op[0] = make_float4(ov[0], ov[1], ov[2], ov[3]);
        op[1] = make_float4(ov[4], ov[5], ov[6], ov[7]);
    }
}

// ---------------- segment max pool (batch sorted, values >= 0) ----------------
__global__ void pool_max(const float* __restrict__ h, const int* __restrict__ batch,
                         float* __restrict__ pooled, int N) {
    int t = blockIdx.x * 256 + threadIdx.x;
    int f = t % 32;
    int i0 = (t / 32) * 32;
    if (i0 >= N) return;
    int gcur = -1;
    float vmax = 0.f;
    for (int j = 0; j < 32; ++j) {
        int i = i0 + j;
        if (i >= N) break;
        int g = batch[i];
        if (g != gcur) {
            if (gcur >= 0) atomicMax((int*)&pooled[gcur * 32 + f], __float_as_int(vmax));
            gcur = g;
            vmax = 0.f;
        }
        vmax = fmaxf(vmax, h[(size_t)i * 32 + f]);
    }
    if (gcur >= 0) atomicMax((int*)&pooled[gcur * 32 + f], __float_as_int(vmax));
}

// ---------------- head ----------------
__global__ void head_kernel(const float* __restrict__ pooled, const float* __restrict__ Wfc,
                            const float* __restrict__ bfc, float* __restrict__ out) {
    int g = threadIdx.x;  // 64 graphs
    float p[32];
#pragma unroll
    for (int f = 0; f < 32; ++f) p[f] = pooled[g * 32 + f];
    float logits[10];
#pragma unroll
    for (int c = 0; c < 10; ++c) {
        float acc = bfc[c];
#pragma unroll
        for (int f = 0; f < 32; ++f) acc += p[f] * Wfc[f * 10 + c];
        logits[c] = acc;
    }
    float m = logits[0];
#pragma unroll
    for (int c = 1; c < 10; ++c) m = fmaxf(m, logits[c]);
    float s = 0.f;
#pragma unroll
    for (int c = 0; c < 10; ++c) s += expf(logits[c] - m);
    float lse = m + logf(s);
#pragma unroll
    for (int c = 0; c < 10; ++c) out[g * 10 + c] = logits[c] - lse;
}

extern "C" void kernel_launch(void* const* d_in, const int* in_sizes, int n_in,
                              void* d_out, int out_size, void* d_ws, size_t ws_size,
                              hipStream_t stream) {
    const float* x   = (const float*)d_in[0];
    const int*   ei  = (const int*)d_in[1];
    const int*   bat = (const int*)d_in[2];
    const float* W1  = (const float*)d_in[3];
    const float* b1  = (const float*)d_in[4];
    const float* W2  = (const float*)d_in[5];
    const float* b2  = (const float*)d_in[6];
    const float* W3  = (const float*)d_in[7];
    const float* b3  = (const float*)d_in[8];
    const float* Wfc = (const float*)d_in[9];
    const float* bfc = (const float*)d_in[10];
    float* out = (float*)d_out;

    const int N = in_sizes[2];        // 100000
    const int E = in_sizes[1] / 2;    // 1600000
    const int K0 = in_sizes[0] / N;   // 512

    const int* src = ei;
    const int* dst = ei + E;

    float* ws = (float*)d_ws;
    float* dinv = ws;                                        // N f32
    unsigned short* HS  = (unsigned short*)(ws + N);         // N*128 bf16 (GEMM out)
    unsigned short* ACT = HS + (size_t)N * 128;              // N*128 bf16 (activations)
    float* H3 = (float*)ACT;                                 // N*32 f32 (aliases ACT, used after GEMM3)
    float* pooled = (float*)(ACT + (size_t)N * 128);         // 2048 f32
    unsigned short* Wt1 = (unsigned short*)(pooled + 2048);  // 128*512 bf16
    unsigned short* Wt2 = Wt1 + 128 * 512;                   // 64*128
    unsigned short* Wt3 = Wt2 + 64 * 128;                    // 32*64
    int* iws = (int*)(Wt3 + 32 * 64);
    int* cnt = iws;                                // N
    int* slab = cnt + N;                           // N*64

    const int nb = (N + 255) / 256;
    const int gb = (N + 63) / 64;
    const int fb = (E + 1023) / 1024;  // 4 edges/thread

    // ---- zero counters/pooled, weight transpose+convert (all independent of fill) ----
    init_kernel<<<nb, 256, 0, stream>>>(cnt, pooled, N);
    wconv<<<(128 * 512 + 255) / 256, 256, 0, stream>>>(W1, Wt1, K0, 128);
    wconv<<<(64 * 128 + 255) / 256, 256, 0, stream>>>(W2, Wt2, 128, 64);
    wconv<<<(32 * 64 + 255) / 256, 256, 0, stream>>>(W3, Wt3, 64, 32);

    const int gath128 = (N + 15) / 16;   // F=128: 16 nodes/block
    const int gath64  = (N + 31) / 32;   // F=64:  32 nodes/block
    const int gath32  = (N + 63) / 64;   // F=32:  64 nodes/block

    // ---- layer 1 GEMM (plain h, bf16 out) fused with slab CSR build ----
    gemm1_fill<<<gb + fb, 256, 0, stream>>>(x, Wt1, HS, N, K0,
                                            src, dst, cnt, slab, E, gb, fb);
    dinv_kernel<<<nb, 256, 0, stream>>>(cnt, dinv, N);
    gather_relu<128, true, false><<<gath128, 256, 0, stream>>>(cnt, slab, dinv, HS, b1, ACT, N);

    // ---- layer 2: 128 -> 64 ----
    mfma_gemm<64, true><<<gb, 256, 0, stream>>>(nullptr, ACT, Wt2, dinv, HS, N, 128);
    gather_relu<64, true, true><<<gath64, 256, 0, stream>>>(cnt, slab, dinv, HS, b2, ACT, N);

    // ---- layer 3: 64 -> 32 ----
    mfma_gemm<32, true><<<gb, 256, 0, stream>>>(nullptr, ACT, Wt3, dinv, HS, N, 64);
    gather_relu<32, false, true><<<gath32, 256, 0, stream>>>(cnt, slab, dinv, HS, b3, H3, N);

    // ---- pool + head ----
    pool_max<<<(((N + 31) / 32) * 32 + 255) / 256, 256, 0, stream>>>(H3, bat, pooled, N);
    head_kernel<<<1, 64, 0, stream>>>(pooled, Wfc, bfc, out);
}

// Round 2
// 533.938 us; speedup vs baseline: 1.1302x; 1.0245x over previous
//
#include <hip/hip_runtime.h>
#include <hip/hip_bf16.h>

// GCN: 3x GCNConv (512->128->64->32) + global max pool + FC(32->10) + log_softmax
// N=100000 nodes, E=1600000 edges, 64 graphs.
//
// Round 8:
//  - Round-7 post-mortem: fused gemm1_fill = 155us ~= fill + gemm1 run back to back.
//    Scattered per-edge atomics/stores are a ~26 Gops/s THROUGHPUT wall, not latency
//    -> overlap and ILP cannot help. Replaced the atomic slab build with a two-pass
//    LDS-staged counting sort:
//      P1 partition_edges: LDS histogram over 1024 dst-buckets (dst>>7), LDS scan,
//         one global atomicAdd per (block,bucket) chunk reservation (195k atomics on
//         64B-padded counters), LDS reorder, run-coalesced packed writes (src<<7|ln).
//      P2 bucket_csr: per-bucket slab built in LDS (128 nodes x 64 slots, LDS atomics),
//         one coalesced 32KB copy out; cnt + dinv fused here.
//  - GEMM1 standalone again with dinv epilogue; gather1 back to prescaled form.

typedef __attribute__((ext_vector_type(8))) short short8;
typedef __attribute__((ext_vector_type(8))) unsigned short ushort8v;
typedef __attribute__((ext_vector_type(4))) float f32x4;

constexpr int NB   = 1024;   // dst buckets (dst>>7), 782 active for N=100000
constexpr int CAPB = 4096;   // edge capacity per bucket (mean 2046, sd ~45)
constexpr int EPB  = 6400;   // edges per partition block

__device__ __forceinline__ unsigned short f2bf(float f) {
    __hip_bfloat16 h = __float2bfloat16(f);
    return *(unsigned short*)&h;
}
__device__ __forceinline__ float bfu2f(unsigned short u) {
    unsigned int v = ((unsigned int)u) << 16;
    return __uint_as_float(v);
}

// ---------------- init: zero bucket counters + pooled ----------------
__global__ void init_kernel(int* __restrict__ bcnt, float* __restrict__ pooled) {
    int i = blockIdx.x * 256 + threadIdx.x;
    if (i < NB * 16) bcnt[i] = 0;
    if (i < 64 * 32) pooled[i] = 0.0f;  // post-relu values >= 0
}

// ---------------- P1: partition edges into dst-buckets (LDS-staged) ----------------
__global__ __launch_bounds__(256) void partition_edges(
        const int* __restrict__ src, const int* __restrict__ dst,
        int* __restrict__ bcnt, unsigned* __restrict__ bucketed, int E) {
    __shared__ unsigned h[NB], rs[NB], cur[NB], gs[NB];
    __shared__ unsigned wtot[4];
    __shared__ unsigned ebuf[EPB];
    __shared__ unsigned short ebkt[EPB];

    const int t = threadIdx.x;
    const int e0 = blockIdx.x * EPB;
    const int nloc = min(EPB, E - e0);

    for (int i = t; i < NB; i += 256) h[i] = 0;
    __syncthreads();

    // phase 1: histogram
    for (int i = t; i < nloc; i += 256) {
        int d = dst[e0 + i];
        atomicAdd(&h[d >> 7], 1u);
    }
    __syncthreads();

    // phase 2: exclusive scan over 1024 buckets (4 per thread) + global reservation
    const unsigned b0 = 4u * t;
    unsigned s0 = h[b0], s1 = h[b0 + 1], s2 = h[b0 + 2], s3 = h[b0 + 3];
    unsigned tsum = s0 + s1 + s2 + s3;
    unsigned scan = tsum;
#pragma unroll
    for (int off = 1; off < 64; off <<= 1) {
        unsigned v = __shfl_up(scan, off, 64);
        if ((t & 63) >= off) scan += v;
    }
    if ((t & 63) == 63) wtot[t >> 6] = scan;
    __syncthreads();
    unsigned woff = 0;
    for (int w = 0; w < (t >> 6); ++w) woff += wtot[w];
    unsigned excl = woff + scan - tsum;
    rs[b0] = excl;                 cur[b0] = excl;
    rs[b0 + 1] = excl + s0;        cur[b0 + 1] = excl + s0;
    rs[b0 + 2] = excl + s0 + s1;   cur[b0 + 2] = excl + s0 + s1;
    rs[b0 + 3] = excl + s0 + s1 + s2; cur[b0 + 3] = excl + s0 + s1 + s2;
    if (s0) gs[b0]     = (unsigned)atomicAdd(&bcnt[(b0) * 16], (int)s0);
    if (s1) gs[b0 + 1] = (unsigned)atomicAdd(&bcnt[(b0 + 1) * 16], (int)s1);
    if (s2) gs[b0 + 2] = (unsigned)atomicAdd(&bcnt[(b0 + 2) * 16], (int)s2);
    if (s3) gs[b0 + 3] = (unsigned)atomicAdd(&bcnt[(b0 + 3) * 16], (int)s3);
    __syncthreads();

    // phase 3: placement into LDS, ordered by (bucket, rank)
    for (int i = t; i < nloc; i += 256) {
        int d = dst[e0 + i];
        int s = src[e0 + i];
        int b = d >> 7;
        unsigned p = atomicAdd(&cur[b], 1u);
        ebuf[p] = ((unsigned)s << 7) | (unsigned)(d & 127);
        ebkt[p] = (unsigned short)b;
    }
    __syncthreads();

    // phase 4: run-coalesced writeout
    for (int p = t; p < nloc; p += 256) {
        unsigned v = ebuf[p];
        int b = ebkt[p];
        unsigned g = gs[b] + ((unsigned)p - rs[b]);
        if (g < CAPB) bucketed[(size_t)b * CAPB + g] = v;
    }
}

// ---------------- P2: per-bucket CSR (slab) build in LDS ----------------
__global__ __launch_bounds__(256) void bucket_csr(
        const unsigned* __restrict__ bucketed, const int* __restrict__ bcnt,
        int* __restrict__ cnt, int* __restrict__ slab, float* __restrict__ dinv, int N) {
    __shared__ int lcnt[128];
    __shared__ unsigned lslab[128 * 64];   // 32 KB

    const int b = blockIdx.x;
    const int t = threadIdx.x;
    if (t < 128) lcnt[t] = 0;
    __syncthreads();

    int nE = bcnt[b * 16];
    if (nE > CAPB) nE = CAPB;
    const unsigned* bb = bucketed + (size_t)b * CAPB;
    for (int e = t; e < nE; e += 256) {
        unsigned v = bb[e];
        int ln = v & 127;
        int pos = atomicAdd(&lcnt[ln], 1);
        if (pos < 64) lslab[ln * 64 + pos] = v >> 7;
    }
    __syncthreads();

    const int node0 = b * 128;
    const int nnodes = min(128, N - node0);
    if (nnodes <= 0) return;
    // coalesced slab copy (garbage beyond each node's deg is never read)
    const int tot4 = (nnodes * 64) / 4;
    int4* gout = (int4*)&slab[(size_t)node0 * 64];
    const int4* lin = (const int4*)lslab;
    for (int i = t; i < tot4; i += 256) gout[i] = lin[i];
    if (t < nnodes) {
        int deg = lcnt[t];
        cnt[node0 + t] = deg;
        dinv[node0 + t] = rsqrtf(1.0f + (float)deg);
    }
}

// ---------------- W[K][N] f32 -> Wt[N][K] bf16 ----------------
__global__ void wconv(const float* __restrict__ W, unsigned short* __restrict__ Wt,
                      int K, int N) {
    int idx = blockIdx.x * 256 + threadIdx.x;
    if (idx < N * K) {
        int n = idx / K, k = idx % K;
        Wt[idx] = f2bf(W[(size_t)k * N + n]);
    }
}

// ---------------- MFMA GEMM: C_bf16[M x NOUT] = dinv .* (A[M x K] @ Wt^T) ----------
template <int NOUT, bool A_BF16>
__global__ __launch_bounds__(256) void mfma_gemm(
        const float* __restrict__ Af, const unsigned short* __restrict__ Ab,
        const unsigned short* __restrict__ Wt, const float* __restrict__ dinv,
        unsigned short* __restrict__ C, int M, int K) {
    constexpr int NT = NOUT / 16;            // col tiles per wave: 8/4/2
    constexpr int CH = 136;                  // shorts per chunk (16*8 + 8 pad)

    __shared__ short As[16 * CH];            // 16 chunks (4 rowgroups x 4 kquads)
    __shared__ short Bs[NT * 4 * CH];        // NT*4 chunks

    const int t = threadIdx.x;
    const int w = t >> 6;                    // wave 0..3
    const int lane = t & 63;
    const int row0 = blockIdx.x * 64;

    f32x4 acc[NT];
#pragma unroll
    for (int c = 0; c < NT; ++c) acc[c] = (f32x4){0.f, 0.f, 0.f, 0.f};

    const int ar = t >> 2;                   // A row 0..63
    const int aq = t & 3;                    // A k-quad
    const int arow = row0 + ar;
    const int a_lds = ((ar >> 4) * 4 + aq) * CH + (ar & 15) * 8;

    const int bn = t >> 1;                   // Wt row (col of W)
    const int bh = t & 1;                    // k-half
    const int b_lds0 = ((bn >> 4) * 4 + 2 * bh) * CH + (bn & 15) * 8;

    for (int k0 = 0; k0 < K; k0 += 32) {
        short8 apack;
        if (A_BF16) {
            if (arow < M) apack = *(const short8*)&Ab[(size_t)arow * K + k0 + aq * 8];
            else apack = (short8){0, 0, 0, 0, 0, 0, 0, 0};
        } else {
            float4 u0 = make_float4(0.f, 0.f, 0.f, 0.f), u1 = u0;
            if (arow < M) {
                const float* ap = Af + (size_t)arow * K + k0 + aq * 8;
                u0 = *(const float4*)ap;
                u1 = *(const float4*)(ap + 4);
            }
            apack[0] = (short)f2bf(u0.x); apack[1] = (short)f2bf(u0.y);
            apack[2] = (short)f2bf(u0.z); apack[3] = (short)f2bf(u0.w);
            apack[4] = (short)f2bf(u1.x); apack[5] = (short)f2bf(u1.y);
            apack[6] = (short)f2bf(u1.z); apack[7] = (short)f2bf(u1.w);
        }
        short8 w0, w1;
        if (t < 2 * NOUT) {
            const unsigned short* wp = Wt + (size_t)bn * K + k0 + 16 * bh;
            w0 = *(const short8*)wp;
            w1 = *(const short8*)(wp + 8);
        }
        __syncthreads();
        *(short8*)&As[a_lds] = apack;
        if (t < 2 * NOUT) {
            *(short8*)&Bs[b_lds0] = w0;
            *(short8*)&Bs[b_lds0 + CH] = w1;
        }
        __syncthreads();

        short8 a = *(short8*)&As[(w * 4 + (lane >> 4)) * CH + (lane & 15) * 8];
#pragma unroll
        for (int c = 0; c < NT; ++c) {
            short8 b = *(short8*)&Bs[(c * 4 + (lane >> 4)) * CH + (lane & 15) * 8];
            acc[c] = __builtin_amdgcn_mfma_f32_16x16x32_bf16(a, b, acc[c], 0, 0, 0);
        }
    }

    const int q = lane >> 4, i = lane & 15;
#pragma unroll
    for (int reg = 0; reg < 4; ++reg) {
        int row = row0 + w * 16 + q * 4 + reg;
        if (row < M) {
            float di = dinv[row];
#pragma unroll
            for (int c = 0; c < NT; ++c)
                C[(size_t)row * NOUT + c * 16 + i] = f2bf(di * acc[c][reg]);
        }
    }
}

// ---------------- gather (bf16 hs prescaled by dinv, slab adjacency) ----------------
// out = relu(dinv .* (hs[i] + sum_in hs[src]) + b)
template <int F, bool OUT_BF16>
__global__ void gather_relu(const int* __restrict__ cnt, const int* __restrict__ slab,
                            const float* __restrict__ dinv,
                            const unsigned short* __restrict__ hs,
                            const float* __restrict__ bias, void* __restrict__ outv, int N) {
    constexpr int F8 = F / 8;          // lanes per node (16/8/4)
    constexpr int NPB = 256 / F8;
    const int node = blockIdx.x * NPB + threadIdx.x / F8;
    if (node >= N) return;
    const int lane = threadIdx.x % F8;
    const size_t fo = (size_t)lane * 8;

    float acc[8];
    {
        ushort8v s = *(const ushort8v*)&hs[(size_t)node * F + fo];
#pragma unroll
        for (int i = 0; i < 8; ++i) acc[i] = bfu2f(s[i]);
    }
    int deg = cnt[node];
    if (deg > 64) deg = 64;
    const int* sl = slab + (size_t)node * 64;

    int j = 0;
    for (; j + 8 <= deg; j += 8) {
        int4 a4 = *(const int4*)&sl[j];
        int4 b4 = *(const int4*)&sl[j + 4];
        ushort8v v0 = *(const ushort8v*)&hs[(size_t)a4.x * F + fo];
        ushort8v v1 = *(const ushort8v*)&hs[(size_t)a4.y * F + fo];
        ushort8v v2 = *(const ushort8v*)&hs[(size_t)a4.z * F + fo];
        ushort8v v3 = *(const ushort8v*)&hs[(size_t)a4.w * F + fo];
        ushort8v v4 = *(const ushort8v*)&hs[(size_t)b4.x * F + fo];
        ushort8v v5 = *(const ushort8v*)&hs[(size_t)b4.y * F + fo];
        ushort8v v6 = *(const ushort8v*)&hs[(size_t)b4.z * F + fo];
        ushort8v v7 = *(const ushort8v*)&hs[(size_t)b4.w * F + fo];
#pragma unroll
        for (int i = 0; i < 8; ++i)
            acc[i] += ((bfu2f(v0[i]) + bfu2f(v1[i])) + (bfu2f(v2[i]) + bfu2f(v3[i]))) +
                      ((bfu2f(v4[i]) + bfu2f(v5[i])) + (bfu2f(v6[i]) + bfu2f(v7[i])));
    }
    for (; j + 4 <= deg; j += 4) {
        int4 s4 = *(const int4*)&sl[j];
        ushort8v v0 = *(const ushort8v*)&hs[(size_t)s4.x * F + fo];
        ushort8v v1 = *(const ushort8v*)&hs[(size_t)s4.y * F + fo];
        ushort8v v2 = *(const ushort8v*)&hs[(size_t)s4.z * F + fo];
        ushort8v v3 = *(const ushort8v*)&hs[(size_t)s4.w * F + fo];
#pragma unroll
        for (int i = 0; i < 8; ++i)
            acc[i] += (bfu2f(v0[i]) + bfu2f(v1[i])) + (bfu2f(v2[i]) + bfu2f(v3[i]));
    }
    for (; j < deg; ++j) {
        int s = sl[j];
        ushort8v v = *(const ushort8v*)&hs[(size_t)s * F + fo];
#pragma unroll
        for (int i = 0; i < 8; ++i) acc[i] += bfu2f(v[i]);
    }

    const float di = dinv[node];
    if (OUT_BF16) {
        ushort8v o;
#pragma unroll
        for (int i = 0; i < 8; ++i) o[i] = f2bf(fmaxf(di * acc[i] + bias[fo + i], 0.f));
        *(ushort8v*)&((unsigned short*)outv)[(size_t)node * F + fo] = o;
    } else {
        float ov[8];
#pragma unroll
        for (int i = 0; i < 8; ++i) ov[i] = fmaxf(di * acc[i] + bias[fo + i], 0.f);
        float4* op = (float4*)&((float*)outv)[(size_t)node * F + fo];
        op[0] = make_float4(ov[0], ov[1], ov[2], ov[3]);
        op[1] = make_float4(ov[4], ov[5], ov[6], ov[7]);
    }
}

// ---------------- segment max pool (batch sorted, values >= 0) ----------------
__global__ void pool_max(const float* __restrict__ h, const int* __restrict__ batch,
                         float* __restrict__ pooled, int N) {
    int t = blockIdx.x * 256 + threadIdx.x;
    int f = t % 32;
    int i0 = (t / 32) * 32;
    if (i0 >= N) return;
    int gcur = -1;
    float vmax = 0.f;
    for (int j = 0; j < 32; ++j) {
        int i = i0 + j;
        if (i >= N) break;
        int g = batch[i];
        if (g != gcur) {
            if (gcur >= 0) atomicMax((int*)&pooled[gcur * 32 + f], __float_as_int(vmax));
            gcur = g;
            vmax = 0.f;
        }
        vmax = fmaxf(vmax, h[(size_t)i * 32 + f]);
    }
    if (gcur >= 0) atomicMax((int*)&pooled[gcur * 32 + f], __float_as_int(vmax));
}

// ---------------- head ----------------
__global__ void head_kernel(const float* __restrict__ pooled, const float* __restrict__ Wfc,
                            const float* __restrict__ bfc, float* __restrict__ out) {
    int g = threadIdx.x;  // 64 graphs
    float p[32];
#pragma unroll
    for (int f = 0; f < 32; ++f) p[f] = pooled[g * 32 + f];
    float logits[10];
#pragma unroll
    for (int c = 0; c < 10; ++c) {
        float acc = bfc[c];
#pragma unroll
        for (int f = 0; f < 32; ++f) acc += p[f] * Wfc[f * 10 + c];
        logits[c] = acc;
    }
    float m = logits[0];
#pragma unroll
    for (int c = 1; c < 10; ++c) m = fmaxf(m, logits[c]);
    float s = 0.f;
#pragma unroll
    for (int c = 0; c < 10; ++c) s += expf(logits[c] - m);
    float lse = m + logf(s);
#pragma unroll
    for (int c = 0; c < 10; ++c) out[g * 10 + c] = logits[c] - lse;
}

extern "C" void kernel_launch(void* const* d_in, const int* in_sizes, int n_in,
                              void* d_out, int out_size, void* d_ws, size_t ws_size,
                              hipStream_t stream) {
    const float* x   = (const float*)d_in[0];
    const int*   ei  = (const int*)d_in[1];
    const int*   bat = (const int*)d_in[2];
    const float* W1  = (const float*)d_in[3];
    const float* b1  = (const float*)d_in[4];
    const float* W2  = (const float*)d_in[5];
    const float* b2  = (const float*)d_in[6];
    const float* W3  = (const float*)d_in[7];
    const float* b3  = (const float*)d_in[8];
    const float* Wfc = (const float*)d_in[9];
    const float* bfc = (const float*)d_in[10];
    float* out = (float*)d_out;

    const int N = in_sizes[2];        // 100000
    const int E = in_sizes[1] / 2;    // 1600000
    const int K0 = in_sizes[0] / N;   // 512

    const int* src = ei;
    const int* dst = ei + E;

    float* ws = (float*)d_ws;
    float* dinv = ws;                                        // N f32
    unsigned short* HS  = (unsigned short*)(ws + N);         // N*128 bf16 (GEMM out)
    unsigned short* ACT = HS + (size_t)N * 128;              // N*128 bf16 (activations)
    float* H3 = (float*)ACT;                                 // N*32 f32 (aliases ACT, used after GEMM3)
    float* pooled = (float*)(ACT + (size_t)N * 128);         // 2048 f32
    unsigned short* Wt1 = (unsigned short*)(pooled + 2048);  // 128*512 bf16
    unsigned short* Wt2 = Wt1 + 128 * 512;                   // 64*128
    unsigned short* Wt3 = Wt2 + 64 * 128;                    // 32*64
    int* cnt = (int*)(Wt3 + 32 * 64);                        // N
    int* slab = cnt + N;                                     // N*64
    int* bcnt = slab + (size_t)N * 64;                       // NB*16 (64B-padded counters)
    unsigned* bucketed = (unsigned*)(bcnt + NB * 16);        // NB*CAPB packed (src<<7|ln)

    const int gb = (N + 63) / 64;
    const int NBUCK = (N + 127) >> 7;   // 782 active buckets

    // ---- zero bucket counters + pooled; weight transpose/convert ----
    init_kernel<<<64, 256, 0, stream>>>(bcnt, pooled);
    wconv<<<(128 * 512 + 255) / 256, 256, 0, stream>>>(W1, Wt1, K0, 128);
    wconv<<<(64 * 128 + 255) / 256, 256, 0, stream>>>(W2, Wt2, 128, 64);
    wconv<<<(32 * 64 + 255) / 256, 256, 0, stream>>>(W3, Wt3, 64, 32);

    // ---- CSR build: partition by dst-bucket, then per-bucket LDS slab ----
    partition_edges<<<(E + EPB - 1) / EPB, 256, 0, stream>>>(src, dst, bcnt, bucketed, E);
    bucket_csr<<<NBUCK, 256, 0, stream>>>(bucketed, bcnt, cnt, slab, dinv, N);

    const int gath128 = (N + 15) / 16;   // F=128: 16 nodes/block
    const int gath64  = (N + 31) / 32;   // F=64:  32 nodes/block
    const int gath32  = (N + 63) / 64;   // F=32:  64 nodes/block

    // ---- layer 1: 512 -> 128 (A = x f32) ----
    mfma_gemm<128, false><<<gb, 256, 0, stream>>>(x, nullptr, Wt1, dinv, HS, N, K0);
    gather_relu<128, true><<<gath128, 256, 0, stream>>>(cnt, slab, dinv, HS, b1, ACT, N);

    // ---- layer 2: 128 -> 64 ----
    mfma_gemm<64, true><<<gb, 256, 0, stream>>>(nullptr, ACT, Wt2, dinv, HS, N, 128);
    gather_relu<64, true><<<gath64, 256, 0, stream>>>(cnt, slab, dinv, HS, b2, ACT, N);

    // ---- layer 3: 64 -> 32 ----
    mfma_gemm<32, true><<<gb, 256, 0, stream>>>(nullptr, ACT, Wt3, dinv, HS, N, 64);
    gather_relu<32, false><<<gath32, 256, 0, stream>>>(cnt, slab, dinv, HS, b3, H3, N);

    // ---- pool + head ----
    pool_max<<<(((N + 31) / 32) * 32 + 255) / 256, 256, 0, stream>>>(H3, bat, pooled, N);
    head_kernel<<<1, 64, 0, stream>>>(pooled, Wfc, bfc, out);
}

// Round 3
// 503.176 us; speedup vs baseline: 1.1993x; 1.0611x over previous
//
#include <hip/hip_runtime.h>
#include <hip/hip_bf16.h>

// GCN: 3x GCNConv (512->128->64->32) + global max pool + FC(32->10) + log_softmax
// N=100000 nodes, E=1600000 edges, 64 graphs.
//
// Round 9:
//  - Round-8 post-mortem: CSR sort-build works (no kernel >120us). Remaining cost is
//    the serial chain + ~100MB of intermediate round-trips (ACT, H3) and launches.
//  - Fused each gather with the NEXT per-node op (block-local):
//      gather1+gemm2 (tile@W2 via MFMA in-block), gather2+gemm3, gather3+pool.
//    ACT/H3 buffers eliminated; 13 kernels -> 8.
//  - setup_kernel merges init + 3x wconv.

typedef __attribute__((ext_vector_type(8))) short short8;
typedef __attribute__((ext_vector_type(8))) unsigned short ushort8v;
typedef __attribute__((ext_vector_type(4))) float f32x4;

constexpr int NB   = 1024;   // dst buckets (dst>>7)
constexpr int CAPB = 4096;   // edge capacity per bucket (mean 2046, sd ~45)
constexpr int EPB  = 6400;   // edges per partition block

__device__ __forceinline__ unsigned short f2bf(float f) {
    __hip_bfloat16 h = __float2bfloat16(f);
    return *(unsigned short*)&h;
}
__device__ __forceinline__ float bfu2f(unsigned short u) {
    unsigned int v = ((unsigned int)u) << 16;
    return __uint_as_float(v);
}

// ---------------- setup: zero bucket counters + pooled, transpose/convert weights ---
__global__ void setup_kernel(const float* __restrict__ W1, const float* __restrict__ W2,
                             const float* __restrict__ W3,
                             unsigned short* __restrict__ Wt1, unsigned short* __restrict__ Wt2,
                             unsigned short* __restrict__ Wt3,
                             int* __restrict__ bcnt, float* __restrict__ pooled) {
    int t = blockIdx.x * 256 + threadIdx.x;
    if (t < NB * 16) bcnt[t] = 0;
    if (t < 64 * 32) pooled[t] = 0.0f;          // post-relu values >= 0
    if (t < 128 * 512) {                         // Wt1[n][k] = W1[k][n], 512x128
        int n = t >> 9, k = t & 511;
        Wt1[t] = f2bf(W1[(size_t)k * 128 + n]);
    } else if (t < 128 * 512 + 64 * 128) {       // Wt2, 128x64
        int u = t - 128 * 512;
        int n = u >> 7, k = u & 127;
        Wt2[u] = f2bf(W2[(size_t)k * 64 + n]);
    } else if (t < 128 * 512 + 64 * 128 + 32 * 64) {  // Wt3, 64x32
        int u = t - (128 * 512 + 64 * 128);
        int n = u >> 6, k = u & 63;
        Wt3[u] = f2bf(W3[(size_t)k * 32 + n]);
    }
}

// ---------------- P1: partition edges into dst-buckets (LDS-staged) ----------------
__global__ __launch_bounds__(256) void partition_edges(
        const int* __restrict__ src, const int* __restrict__ dst,
        int* __restrict__ bcnt, unsigned* __restrict__ bucketed, int E) {
    __shared__ unsigned h[NB], rs[NB], cur[NB], gs[NB];
    __shared__ unsigned wtot[4];
    __shared__ unsigned ebuf[EPB];
    __shared__ unsigned short ebkt[EPB];

    const int t = threadIdx.x;
    const int e0 = blockIdx.x * EPB;
    const int nloc = min(EPB, E - e0);

    for (int i = t; i < NB; i += 256) h[i] = 0;
    __syncthreads();

    for (int i = t; i < nloc; i += 256) {
        int d = dst[e0 + i];
        atomicAdd(&h[d >> 7], 1u);
    }
    __syncthreads();

    const unsigned b0 = 4u * t;
    unsigned s0 = h[b0], s1 = h[b0 + 1], s2 = h[b0 + 2], s3 = h[b0 + 3];
    unsigned tsum = s0 + s1 + s2 + s3;
    unsigned scan = tsum;
#pragma unroll
    for (int off = 1; off < 64; off <<= 1) {
        unsigned v = __shfl_up(scan, off, 64);
        if ((t & 63) >= off) scan += v;
    }
    if ((t & 63) == 63) wtot[t >> 6] = scan;
    __syncthreads();
    unsigned woff = 0;
    for (int w = 0; w < (t >> 6); ++w) woff += wtot[w];
    unsigned excl = woff + scan - tsum;
    rs[b0] = excl;                    cur[b0] = excl;
    rs[b0 + 1] = excl + s0;           cur[b0 + 1] = excl + s0;
    rs[b0 + 2] = excl + s0 + s1;      cur[b0 + 2] = excl + s0 + s1;
    rs[b0 + 3] = excl + s0 + s1 + s2; cur[b0 + 3] = excl + s0 + s1 + s2;
    if (s0) gs[b0]     = (unsigned)atomicAdd(&bcnt[(b0) * 16], (int)s0);
    if (s1) gs[b0 + 1] = (unsigned)atomicAdd(&bcnt[(b0 + 1) * 16], (int)s1);
    if (s2) gs[b0 + 2] = (unsigned)atomicAdd(&bcnt[(b0 + 2) * 16], (int)s2);
    if (s3) gs[b0 + 3] = (unsigned)atomicAdd(&bcnt[(b0 + 3) * 16], (int)s3);
    __syncthreads();

    for (int i = t; i < nloc; i += 256) {
        int d = dst[e0 + i];
        int s = src[e0 + i];
        int b = d >> 7;
        unsigned p = atomicAdd(&cur[b], 1u);
        ebuf[p] = ((unsigned)s << 7) | (unsigned)(d & 127);
        ebkt[p] = (unsigned short)b;
    }
    __syncthreads();

    for (int p = t; p < nloc; p += 256) {
        unsigned v = ebuf[p];
        int b = ebkt[p];
        unsigned g = gs[b] + ((unsigned)p - rs[b]);
        if (g < CAPB) bucketed[(size_t)b * CAPB + g] = v;
    }
}

// ---------------- P2: per-bucket CSR (slab) build in LDS ----------------
__global__ __launch_bounds__(256) void bucket_csr(
        const unsigned* __restrict__ bucketed, const int* __restrict__ bcnt,
        int* __restrict__ cnt, int* __restrict__ slab, float* __restrict__ dinv, int N) {
    __shared__ int lcnt[128];
    __shared__ unsigned lslab[128 * 64];   // 32 KB

    const int b = blockIdx.x;
    const int t = threadIdx.x;
    if (t < 128) lcnt[t] = 0;
    __syncthreads();

    int nE = bcnt[b * 16];
    if (nE > CAPB) nE = CAPB;
    const unsigned* bb = bucketed + (size_t)b * CAPB;
    for (int e = t; e < nE; e += 256) {
        unsigned v = bb[e];
        int ln = v & 127;
        int pos = atomicAdd(&lcnt[ln], 1);
        if (pos < 64) lslab[ln * 64 + pos] = v >> 7;
    }
    __syncthreads();

    const int node0 = b * 128;
    const int nnodes = min(128, N - node0);
    if (nnodes <= 0) return;
    const int tot4 = (nnodes * 64) / 4;
    int4* gout = (int4*)&slab[(size_t)node0 * 64];
    const int4* lin = (const int4*)lslab;
    for (int i = t; i < tot4; i += 256) gout[i] = lin[i];
    if (t < nnodes) {
        int deg = lcnt[t];
        cnt[node0 + t] = deg;
        dinv[node0 + t] = rsqrtf(1.0f + (float)deg);
    }
}

// ---------------- MFMA GEMM: C_bf16[M x NOUT] = dinv .* (A[M x K] @ Wt^T) ----------
template <int NOUT, bool A_BF16>
__global__ __launch_bounds__(256) void mfma_gemm(
        const float* __restrict__ Af, const unsigned short* __restrict__ Ab,
        const unsigned short* __restrict__ Wt, const float* __restrict__ dinv,
        unsigned short* __restrict__ C, int M, int K) {
    constexpr int NT = NOUT / 16;
    constexpr int CH = 136;

    __shared__ short As[16 * CH];
    __shared__ short Bs[NT * 4 * CH];

    const int t = threadIdx.x;
    const int w = t >> 6;
    const int lane = t & 63;
    const int row0 = blockIdx.x * 64;

    f32x4 acc[NT];
#pragma unroll
    for (int c = 0; c < NT; ++c) acc[c] = (f32x4){0.f, 0.f, 0.f, 0.f};

    const int ar = t >> 2;
    const int aq = t & 3;
    const int arow = row0 + ar;
    const int a_lds = ((ar >> 4) * 4 + aq) * CH + (ar & 15) * 8;

    const int bn = t >> 1;
    const int bh = t & 1;
    const int b_lds0 = ((bn >> 4) * 4 + 2 * bh) * CH + (bn & 15) * 8;

    for (int k0 = 0; k0 < K; k0 += 32) {
        short8 apack;
        if (A_BF16) {
            if (arow < M) apack = *(const short8*)&Ab[(size_t)arow * K + k0 + aq * 8];
            else apack = (short8){0, 0, 0, 0, 0, 0, 0, 0};
        } else {
            float4 u0 = make_float4(0.f, 0.f, 0.f, 0.f), u1 = u0;
            if (arow < M) {
                const float* ap = Af + (size_t)arow * K + k0 + aq * 8;
                u0 = *(const float4*)ap;
                u1 = *(const float4*)(ap + 4);
            }
            apack[0] = (short)f2bf(u0.x); apack[1] = (short)f2bf(u0.y);
            apack[2] = (short)f2bf(u0.z); apack[3] = (short)f2bf(u0.w);
            apack[4] = (short)f2bf(u1.x); apack[5] = (short)f2bf(u1.y);
            apack[6] = (short)f2bf(u1.z); apack[7] = (short)f2bf(u1.w);
        }
        short8 w0, w1;
        if (t < 2 * NOUT) {
            const unsigned short* wp = Wt + (size_t)bn * K + k0 + 16 * bh;
            w0 = *(const short8*)wp;
            w1 = *(const short8*)(wp + 8);
        }
        __syncthreads();
        *(short8*)&As[a_lds] = apack;
        if (t < 2 * NOUT) {
            *(short8*)&Bs[b_lds0] = w0;
            *(short8*)&Bs[b_lds0 + CH] = w1;
        }
        __syncthreads();

        short8 a = *(short8*)&As[(w * 4 + (lane >> 4)) * CH + (lane & 15) * 8];
#pragma unroll
        for (int c = 0; c < NT; ++c) {
            short8 b = *(short8*)&Bs[(c * 4 + (lane >> 4)) * CH + (lane & 15) * 8];
            acc[c] = __builtin_amdgcn_mfma_f32_16x16x32_bf16(a, b, acc[c], 0, 0, 0);
        }
    }

    const int q = lane >> 4, i = lane & 15;
#pragma unroll
    for (int reg = 0; reg < 4; ++reg) {
        int row = row0 + w * 16 + q * 4 + reg;
        if (row < M) {
            float di = dinv[row];
#pragma unroll
            for (int c = 0; c < NT; ++c)
                C[(size_t)row * NOUT + c * 16 + i] = f2bf(di * acc[c][reg]);
        }
    }
}

// ---------------- shared gather inner loop (slab adjacency, bf16 rows) -------------
template <int F>
__device__ __forceinline__ void gather_acc(
        const int* __restrict__ cnt, const int* __restrict__ slab,
        const unsigned short* __restrict__ hs, int node, size_t fo, float acc[8]) {
    {
        ushort8v s = *(const ushort8v*)&hs[(size_t)node * F + fo];
#pragma unroll
        for (int i = 0; i < 8; ++i) acc[i] = bfu2f(s[i]);
    }
    int deg = cnt[node];
    if (deg > 64) deg = 64;
    const int* sl = slab + (size_t)node * 64;

    int j = 0;
    for (; j + 8 <= deg; j += 8) {
        int4 a4 = *(const int4*)&sl[j];
        int4 b4 = *(const int4*)&sl[j + 4];
        ushort8v v0 = *(const ushort8v*)&hs[(size_t)a4.x * F + fo];
        ushort8v v1 = *(const ushort8v*)&hs[(size_t)a4.y * F + fo];
        ushort8v v2 = *(const ushort8v*)&hs[(size_t)a4.z * F + fo];
        ushort8v v3 = *(const ushort8v*)&hs[(size_t)a4.w * F + fo];
        ushort8v v4 = *(const ushort8v*)&hs[(size_t)b4.x * F + fo];
        ushort8v v5 = *(const ushort8v*)&hs[(size_t)b4.y * F + fo];
        ushort8v v6 = *(const ushort8v*)&hs[(size_t)b4.z * F + fo];
        ushort8v v7 = *(const ushort8v*)&hs[(size_t)b4.w * F + fo];
#pragma unroll
        for (int i = 0; i < 8; ++i)
            acc[i] += ((bfu2f(v0[i]) + bfu2f(v1[i])) + (bfu2f(v2[i]) + bfu2f(v3[i]))) +
                      ((bfu2f(v4[i]) + bfu2f(v5[i])) + (bfu2f(v6[i]) + bfu2f(v7[i])));
    }
    for (; j + 4 <= deg; j += 4) {
        int4 s4 = *(const int4*)&sl[j];
        ushort8v v0 = *(const ushort8v*)&hs[(size_t)s4.x * F + fo];
        ushort8v v1 = *(const ushort8v*)&hs[(size_t)s4.y * F + fo];
        ushort8v v2 = *(const ushort8v*)&hs[(size_t)s4.z * F + fo];
        ushort8v v3 = *(const ushort8v*)&hs[(size_t)s4.w * F + fo];
#pragma unroll
        for (int i = 0; i < 8; ++i)
            acc[i] += (bfu2f(v0[i]) + bfu2f(v1[i])) + (bfu2f(v2[i]) + bfu2f(v3[i]));
    }
    for (; j < deg; ++j) {
        int s = sl[j];
        ushort8v v = *(const ushort8v*)&hs[(size_t)s * F + fo];
#pragma unroll
        for (int i = 0; i < 8; ++i) acc[i] += bfu2f(v[i]);
    }
}

// ---------------- fused gather+relu (layer l) + linear (layer l+1) ------------------
// Reads hs (prescaled GEMM output of layer l), produces Cout = dinv .* (ACT @ Wt^T)
// where ACT = relu(dinv.*(hs_self + sum hs_nbr) + bias). ACT never hits global.
template <int F, int NOUT>
__global__ __launch_bounds__(256) void gather_gemm(
        const int* __restrict__ cnt, const int* __restrict__ slab,
        const float* __restrict__ dinv, const unsigned short* __restrict__ hs,
        const float* __restrict__ bias, const unsigned short* __restrict__ Wt,
        unsigned short* __restrict__ Cout, int N) {
    constexpr int F8 = F / 8;
    constexpr int NPB = 256 / F8;        // 16 (F=128) or 32 (F=64)
    constexpr int LDA = F + 8;           // pad: 2-way-max LDS bank aliasing
    constexpr int MT = NPB / 16;         // 1 or 2 M-tiles
    constexpr int KS = F / 32;           // 4 or 2 K-steps

    __shared__ short At[NPB * LDA];
    __shared__ short Bs[NOUT * LDA];

    const int t = threadIdx.x;
    const int node0 = blockIdx.x * NPB;
    const int nl = t / F8;
    const int lf = t % F8;
    const int node = node0 + nl;
    const size_t fo = (size_t)lf * 8;

    // stage Wt -> Bs ([NOUT][F] row-major, padded)
#pragma unroll
    for (int idx = t * 8; idx < NOUT * F; idx += 256 * 8) {
        int r = idx / F, k = idx % F;
        *(short8*)&Bs[r * LDA + k] = *(const short8*)&Wt[idx];
    }

    // gather + bias + relu -> bf16 row fragment
    short8 arow = (short8){0, 0, 0, 0, 0, 0, 0, 0};
    if (node < N) {
        float acc[8];
        gather_acc<F>(cnt, slab, hs, node, fo, acc);
        const float di = dinv[node];
#pragma unroll
        for (int i = 0; i < 8; ++i)
            arow[i] = (short)f2bf(fmaxf(di * acc[i] + bias[fo + i], 0.f));
    }
    *(short8*)&At[nl * LDA + lf * 8] = arow;
    __syncthreads();

    // per-wave MFMA: wave w handles (m,c) output tile
    const int w = t >> 6, l = t & 63;
    const int m = (MT == 1) ? 0 : (w >> 1);
    const int c = (MT == 1) ? w : (w & 1);
    f32x4 acc4 = (f32x4){0.f, 0.f, 0.f, 0.f};
#pragma unroll
    for (int ks = 0; ks < KS; ++ks) {
        short8 a = *(short8*)&At[(m * 16 + (l & 15)) * LDA + ks * 32 + (l >> 4) * 8];
        short8 b = *(short8*)&Bs[(c * 16 + (l & 15)) * LDA + ks * 32 + (l >> 4) * 8];
        acc4 = __builtin_amdgcn_mfma_f32_16x16x32_bf16(a, b, acc4, 0, 0, 0);
    }
    const int q = l >> 4, i = l & 15;
#pragma unroll
    for (int reg = 0; reg < 4; ++reg) {
        int grow = node0 + m * 16 + q * 4 + reg;
        if (grow < N)
            Cout[(size_t)grow * NOUT + c * 16 + i] = f2bf(dinv[grow] * acc4[reg]);
    }
}

// ---------------- fused gather3 + relu + segment-max pool ----------------
__global__ __launch_bounds__(256) void gather_pool(
        const int* __restrict__ cnt, const int* __restrict__ slab,
        const float* __restrict__ dinv, const unsigned short* __restrict__ hs,
        const float* __restrict__ bias, const int* __restrict__ batch,
        float* __restrict__ pooled, int N) {
    constexpr int F = 32, F8 = 4, NPB = 64;
    __shared__ float P[NPB * 32];
    __shared__ int gbuf[NPB];

    const int t = threadIdx.x;
    const int node0 = blockIdx.x * NPB;
    const int nl = t >> 2, lf = t & 3;
    const int node = node0 + nl;
    const size_t fo = (size_t)lf * 8;

    float ov[8] = {0.f, 0.f, 0.f, 0.f, 0.f, 0.f, 0.f, 0.f};
    if (node < N) {
        float acc[8];
        gather_acc<F>(cnt, slab, hs, node, fo, acc);
        const float di = dinv[node];
#pragma unroll
        for (int i = 0; i < 8; ++i) ov[i] = fmaxf(di * acc[i] + bias[fo + i], 0.f);
    }
#pragma unroll
    for (int i = 0; i < 8; ++i) P[nl * 32 + lf * 8 + i] = ov[i];
    if (t < NPB) gbuf[t] = (node0 + t < N) ? batch[node0 + t] : -1;
    __syncthreads();

    if (t < 32) {
        int gcur = -1;
        float vmax = 0.f;
        for (int j = 0; j < NPB; ++j) {
            int g = gbuf[j];
            if (g < 0) break;
            if (g != gcur) {
                if (gcur >= 0) atomicMax((int*)&pooled[gcur * 32 + t], __float_as_int(vmax));
                gcur = g;
                vmax = 0.f;
            }
            vmax = fmaxf(vmax, P[j * 32 + t]);
        }
        if (gcur >= 0) atomicMax((int*)&pooled[gcur * 32 + t], __float_as_int(vmax));
    }
}

// ---------------- head ----------------
__global__ void head_kernel(const float* __restrict__ pooled, const float* __restrict__ Wfc,
                            const float* __restrict__ bfc, float* __restrict__ out) {
    int g = threadIdx.x;  // 64 graphs
    float p[32];
#pragma unroll
    for (int f = 0; f < 32; ++f) p[f] = pooled[g * 32 + f];
    float logits[10];
#pragma unroll
    for (int c = 0; c < 10; ++c) {
        float acc = bfc[c];
#pragma unroll
        for (int f = 0; f < 32; ++f) acc += p[f] * Wfc[f * 10 + c];
        logits[c] = acc;
    }
    float m = logits[0];
#pragma unroll
    for (int c = 1; c < 10; ++c) m = fmaxf(m, logits[c]);
    float s = 0.f;
#pragma unroll
    for (int c = 0; c < 10; ++c) s += expf(logits[c] - m);
    float lse = m + logf(s);
#pragma unroll
    for (int c = 0; c < 10; ++c) out[g * 10 + c] = logits[c] - lse;
}

extern "C" void kernel_launch(void* const* d_in, const int* in_sizes, int n_in,
                              void* d_out, int out_size, void* d_ws, size_t ws_size,
                              hipStream_t stream) {
    const float* x   = (const float*)d_in[0];
    const int*   ei  = (const int*)d_in[1];
    const int*   bat = (const int*)d_in[2];
    const float* W1  = (const float*)d_in[3];
    const float* b1  = (const float*)d_in[4];
    const float* W2  = (const float*)d_in[5];
    const float* b2  = (const float*)d_in[6];
    const float* W3  = (const float*)d_in[7];
    const float* b3  = (const float*)d_in[8];
    const float* Wfc = (const float*)d_in[9];
    const float* bfc = (const float*)d_in[10];
    float* out = (float*)d_out;

    const int N = in_sizes[2];        // 100000
    const int E = in_sizes[1] / 2;    // 1600000
    const int K0 = in_sizes[0] / N;   // 512

    const int* src = ei;
    const int* dst = ei + E;

    float* ws = (float*)d_ws;
    float* dinv = ws;                                        // N f32
    unsigned short* HS  = (unsigned short*)(ws + N);         // N*128 bf16 (gemm1 out)
    unsigned short* HS2 = HS + (size_t)N * 128;              // N*64 bf16
    unsigned short* HS3 = HS2 + (size_t)N * 64;              // N*32 bf16
    float* pooled = (float*)(HS3 + (size_t)N * 32);          // 2048 f32
    unsigned short* Wt1 = (unsigned short*)(pooled + 2048);  // 128*512 bf16
    unsigned short* Wt2 = Wt1 + 128 * 512;                   // 64*128
    unsigned short* Wt3 = Wt2 + 64 * 128;                    // 32*64
    int* cnt = (int*)(Wt3 + 32 * 64);                        // N
    int* slab = cnt + N;                                     // N*64
    int* bcnt = slab + (size_t)N * 64;                       // NB*16 (64B-padded counters)
    unsigned* bucketed = (unsigned*)(bcnt + NB * 16);        // NB*CAPB packed (src<<7|ln)

    const int gb = (N + 63) / 64;
    const int NBUCK = (N + 127) >> 7;

    // ---- setup (zero counters/pooled, convert weights) ----
    setup_kernel<<<(128 * 512 + 64 * 128 + 32 * 64 + 255) / 256, 256, 0, stream>>>(
        W1, W2, W3, Wt1, Wt2, Wt3, bcnt, pooled);

    // ---- CSR build: partition by dst-bucket, then per-bucket LDS slab ----
    partition_edges<<<(E + EPB - 1) / EPB, 256, 0, stream>>>(src, dst, bcnt, bucketed, E);
    bucket_csr<<<NBUCK, 256, 0, stream>>>(bucketed, bcnt, cnt, slab, dinv, N);

    // ---- layer 1 GEMM: 512 -> 128 (A = x f32) ----
    mfma_gemm<128, false><<<gb, 256, 0, stream>>>(x, nullptr, Wt1, dinv, HS, N, K0);

    // ---- gather1 + gemm2 fused: HS -> HS2 ----
    gather_gemm<128, 64><<<(N + 15) / 16, 256, 0, stream>>>(
        cnt, slab, dinv, HS, b1, Wt2, HS2, N);

    // ---- gather2 + gemm3 fused: HS2 -> HS3 ----
    gather_gemm<64, 32><<<(N + 31) / 32, 256, 0, stream>>>(
        cnt, slab, dinv, HS2, b2, Wt3, HS3, N);

    // ---- gather3 + relu + pool fused ----
    gather_pool<<<(N + 63) / 64, 256, 0, stream>>>(cnt, slab, dinv, HS3, b3, bat, pooled, N);

    // ---- head ----
    head_kernel<<<1, 64, 0, stream>>>(pooled, Wfc, bfc, out);
}